// Round 7
// baseline (3060.375 us; speedup 1.0000x reference)
//
#include <hip/hip_runtime.h>
#include <hip/hip_bf16.h>

#define BB   64
#define QQ   256
#define TT   256
#define CD   258          // 2 + NC
#define NM   256          // square assignment size
#define BIGF 1000000000.0f
#define LROWS 152         // rows cached in LDS (152 KB dynamic)

// ---------------------------------------------------------------------------
// Kernel 1: per-(b,q) softmax stats (max and sum of exp(x-max)) over NC=256
// ---------------------------------------------------------------------------
__global__ __launch_bounds__(256) void sm_stats(const float* __restrict__ outs,
                                                float* __restrict__ rmax,
                                                float* __restrict__ rsum) {
    int row = blockIdx.x;            // b*Q + q
    int tid = threadIdx.x;
    float x = outs[(size_t)row * CD + 2 + tid];

    __shared__ float sw[5];
    float m = x;
#pragma unroll
    for (int off = 32; off; off >>= 1) m = fmaxf(m, __shfl_down(m, off, 64));
    if ((tid & 63) == 0) sw[tid >> 6] = m;
    __syncthreads();
    if (tid == 0) sw[4] = fmaxf(fmaxf(sw[0], sw[1]), fmaxf(sw[2], sw[3]));
    __syncthreads();
    float mx = sw[4];

    float s = expf(x - mx);
#pragma unroll
    for (int off = 32; off; off >>= 1) s += __shfl_down(s, off, 64);
    __syncthreads();
    if ((tid & 63) == 0) sw[tid >> 6] = s;
    __syncthreads();
    if (tid == 0) {
        rmax[row] = mx;
        rsum[row] = sw[0] + sw[1] + sw[2] + sw[3];
    }
}

// ---------------------------------------------------------------------------
// Kernel 2: build cost matrix C[b][t][q]
// ---------------------------------------------------------------------------
__global__ __launch_bounds__(256) void build_cost(const float* __restrict__ outs,
                                                  const float* __restrict__ tpos,
                                                  const int* __restrict__ tids,
                                                  const float* __restrict__ rmax,
                                                  const float* __restrict__ rsum,
                                                  float* __restrict__ C) {
    int bt = blockIdx.x;             // b*T + t
    int b  = bt >> 8;
    int q  = threadIdx.x;

    int   id = tids[bt];
    float tx = tpos[2 * bt];
    float ty = tpos[2 * bt + 1];

    const float* orow = outs + (size_t)(b * QQ + q) * CD;
    float dx = orow[0] - tx;
    float dy = orow[1] - ty;
    float d  = sqrtf(dx * dx + dy * dy);
    float bbox = fminf(d, 100.0f);
    if (id <= 0) bbox = 100.0f;

    int   rq  = b * QQ + q;
    float cls = expf(orow[2 + id] - rmax[rq]) / rsum[rq];

    C[(size_t)bt * QQ + q] = bbox - cls;
}

// ---------------------------------------------------------------------------
// Kernel 3: EXACT reference JV, one wave per block (own CU).
// - payload-carrying DPP min reduce (value + packed (row+1, j)); tie -> lower
//   lane. DPP windows (shr 1/2/4/8, bcast15/31) merge disjoint lower windows,
//   so tie-resolution == global first-index == reference argmin.
// - minv[used] folded to BIGF (same compare values as reference's masked big).
// - register augment walk (way packed 2x16b per lane, readlane chain) + one
//   parallel LDS path-shift apply.
// Bitwise-identical arithmetic/trajectory to the reference.
// ---------------------------------------------------------------------------
__device__ __forceinline__ float sel4f(const float a[4], int s) {
    float r = a[0];
    r = (s == 1) ? a[1] : r;
    r = (s == 2) ? a[2] : r;
    r = (s == 3) ? a[3] : r;
    return r;
}

template <int CTRL, int RM>
__device__ __forceinline__ void dppstep(float& x, int& p) {
    float fy = __int_as_float(__builtin_amdgcn_update_dpp(
        __float_as_int(x), __float_as_int(x), CTRL, RM, 0xF, false));
    int   py = __builtin_amdgcn_update_dpp(p, p, CTRL, RM, 0xF, false);
    p = (fy <= x) ? py : p;      // tie -> incoming (lower lane) = first index
    x = fminf(x, fy);
}

__global__ __launch_bounds__(64) void jv_solve(const float* __restrict__ Call,
                                               float* __restrict__ outIdx) {
    const int b    = blockIdx.x;
    const int lane = threadIdx.x;
    const float* cost = Call + (size_t)b * NM * NM;

    __shared__ float u_s[NM + 1];
    __shared__ int   p_s[NM + 1];
    __shared__ int   path_s[NM + 1];
    extern __shared__ float crow[];          // [LROWS][NM]

    // stage rows 0..LROWS-1 into LDS (bit-identical copy)
#pragma unroll 4
    for (int r = 0; r < LROWS; ++r) {
        float4 x = *(const float4*)(cost + (size_t)r * NM + lane * 4);
        *(float4*)(crow + r * NM + lane * 4) = x;
    }
    for (int k = lane; k <= NM; k += 64) {
        u_s[k] = 0.0f;
        p_s[k] = -1;
    }
    // single wave: lockstep, no barriers needed anywhere

    float v[4] = {0.0f, 0.0f, 0.0f, 0.0f};   // column duals, persist

    for (int i = 0; i < NM; ++i) {
        float4 cr;
        if (i < LROWS) cr = *(const float4*)(crow + i * NM + lane * 4);
        else           cr = *(const float4*)(cost + (size_t)i * NM + lane * 4);

        if (lane == 0) p_s[NM] = i;

        // p[j], u[p[j]] static during one scan
        int   pj[4];
        float ureg[4];
#pragma unroll
        for (int s = 0; s < 4; ++s) {
            pj[s]   = p_s[lane * 4 + s];
            ureg[s] = (pj[s] >= 0) ? u_s[pj[s]] : 0.0f;
        }
        const float uof[4] = {ureg[0], ureg[1], ureg[2], ureg[3]};
        float minv[4] = {BIGF, BIGF, BIGF, BIGF};
        int   way[4]  = {NM, NM, NM, NM};
        unsigned usedm = 0;
        float ui = 0.0f;
        int   j0 = NM;
        float u0 = 0.0f;

        while (true) {
            // mark j0 used at body start (as reference); fold minv[j0]=BIGF
            {
                bool own = (j0 >> 2) == lane;
                if (own) usedm |= 1u << (j0 & 3);
#pragma unroll
                for (int s = 0; s < 4; ++s) {
                    bool mk = own && ((j0 & 3) == s);
                    minv[s] = mk ? BIGF : minv[s];
                }
            }

            float c4[4] = {cr.x, cr.y, cr.z, cr.w};
#pragma unroll
            for (int s = 0; s < 4; ++s) {
                float cur = c4[s] - u0 - v[s];
                bool  un  = !(usedm & (1u << s));
                bool  bt  = un && (cur < minv[s]);
                minv[s] = bt ? cur : minv[s];
                way[s]  = bt ? j0  : way[s];
            }

            // value chain first (feeds DPP immediately)
            float lv = fminf(fminf(minv[0], minv[1]), fminf(minv[2], minv[3]));
            // payload (first slot achieving lv) — off critical path
            int ls  = (minv[0] == lv) ? 0 : (minv[1] == lv) ? 1
                     : (minv[2] == lv) ? 2 : 3;
            int pjs = (minv[0] == lv) ? pj[0] : (minv[1] == lv) ? pj[1]
                     : (minv[2] == lv) ? pj[2] : pj[3];
            int pay = ((pjs + 1) << 8) | (lane * 4 + ls);

            float x = lv; int p = pay;
            dppstep<0x111, 0xF>(x, p);   // row_shr:1
            dppstep<0x112, 0xF>(x, p);   // row_shr:2
            dppstep<0x114, 0xF>(x, p);   // row_shr:4
            dppstep<0x118, 0xF>(x, p);   // row_shr:8
            dppstep<0x142, 0xA>(x, p);   // row_bcast:15 -> rows 1,3
            dppstep<0x143, 0xC>(x, p);   // row_bcast:31 -> rows 2,3

            int   w     = __builtin_amdgcn_readlane(p, 63);
            float delta = __int_as_float(
                __builtin_amdgcn_readlane(__float_as_int(x), 63));
            int i0n = (w >> 8) - 1;
            int j1  = w & 255;

            // prefetch next row ASAP (overlaps the update ops below)
            if (i0n >= 0) {
                if (i0n < LROWS) cr = *(const float4*)(crow + i0n * NM + lane * 4);
                else             cr = *(const float4*)(cost + (size_t)i0n * NM + lane * 4);
            }
            float usel = sel4f(uof, j1 & 3);
            float u0n  = __int_as_float(__builtin_amdgcn_readlane(
                __float_as_int(usel), j1 >> 2));

            // updates, same order/arithmetic as reference
            ui += delta;
#pragma unroll
            for (int s = 0; s < 4; ++s) {
                bool us = (usedm >> s) & 1;
                v[s]    = us ? (v[s] - delta)    : v[s];
                ureg[s] = us ? (ureg[s] + delta) : ureg[s];
                minv[s] = us ? minv[s] : (minv[s] - delta);
            }
            j0 = j1;
            if (i0n < 0) break;
            u0 = u0n;
        }

        // write back u for used slots (distinct rows)
#pragma unroll
        for (int s = 0; s < 4; ++s)
            if (usedm & (1u << s)) u_s[pj[s]] = ureg[s];
        if (lane == 0) u_s[i] = ui;

        // augment walk in registers: way packed 2x16b per lane
        unsigned wlo = (unsigned)way[0] | ((unsigned)way[1] << 16);
        unsigned whi = (unsigned)way[2] | ((unsigned)way[3] << 16);
        int jj = j0, m = 0;
        while (jj != NM) {
            if (lane == 0) path_s[m] = jj;
            int l  = jj >> 2;
            int lo = __builtin_amdgcn_readlane((int)wlo, l);
            int hi = __builtin_amdgcn_readlane((int)whi, l);
            int wd = (jj & 2) ? hi : lo;
            jj = (jj & 1) ? ((wd >> 16) & 0xffff) : (wd & 0xffff);
            ++m;
        }
        if (lane == 0) path_s[m] = NM;      // terminator: p_s[NM] == i

        // parallel path shift: p[path[k]] = p_old[path[k+1]]
        // (within a batch of 64, all reads issue before any write; across
        //  batches the read set n_{64b+1..} is disjoint from prior writes)
        for (int base = 0; base < m; base += 64) {
            int k = base + lane;
            if (k < m) {
                int nd = path_s[k];
                int pv = p_s[path_s[k + 1]];
                p_s[nd] = pv;
            }
        }
    }

    // outputs as float32: indices[0]=rows (arange), indices[1]=cols
#pragma unroll
    for (int s = 0; s < 4; ++s) {
        int j = lane * 4 + s;
        outIdx[b * TT + j] = (float)j;
        int r = p_s[j];
        outIdx[BB * TT + b * TT + r] = (float)j;
    }
}

// ---------------------------------------------------------------------------
extern "C" void kernel_launch(void* const* d_in, const int* in_sizes, int n_in,
                              void* d_out, int out_size, void* d_ws, size_t ws_size,
                              hipStream_t stream) {
    const float* outs = (const float*)d_in[0];   // (B,Q,258) f32
    const float* tpos = (const float*)d_in[1];   // (B,T,2)   f32
    const int*   tids = (const int*)d_in[2];     // (B,T)     i32

    float* out  = (float*)d_out;
    float* C    = out + 2 * BB * TT;
    float* rmax = (float*)d_ws;
    float* rsum = rmax + BB * QQ;

    hipLaunchKernelGGL(sm_stats,   dim3(BB * QQ), dim3(256), 0, stream, outs, rmax, rsum);
    hipLaunchKernelGGL(build_cost, dim3(BB * TT), dim3(256), 0, stream, outs, tpos, tids, rmax, rsum, C);
    hipLaunchKernelGGL(jv_solve,   dim3(BB),      dim3(64),
                       LROWS * NM * sizeof(float), stream, C, out);
}

// Round 8
// 2823.404 us; speedup vs baseline: 1.0839x; 1.0839x over previous
//
#include <hip/hip_runtime.h>
#include <hip/hip_bf16.h>

#define BB   64
#define QQ   256
#define TT   256
#define CD   258          // 2 + NC
#define NM   256          // square assignment size
#define BIGF 1000000000.0f
#define LROWS 152         // rows cached in LDS (152 KB dynamic)

// ---------------------------------------------------------------------------
// Kernel 1: per-(b,q) softmax stats (max and sum of exp(x-max)) over NC=256
// ---------------------------------------------------------------------------
__global__ __launch_bounds__(256) void sm_stats(const float* __restrict__ outs,
                                                float* __restrict__ rmax,
                                                float* __restrict__ rsum) {
    int row = blockIdx.x;            // b*Q + q
    int tid = threadIdx.x;
    float x = outs[(size_t)row * CD + 2 + tid];

    __shared__ float sw[5];
    float m = x;
#pragma unroll
    for (int off = 32; off; off >>= 1) m = fmaxf(m, __shfl_down(m, off, 64));
    if ((tid & 63) == 0) sw[tid >> 6] = m;
    __syncthreads();
    if (tid == 0) sw[4] = fmaxf(fmaxf(sw[0], sw[1]), fmaxf(sw[2], sw[3]));
    __syncthreads();
    float mx = sw[4];

    float s = expf(x - mx);
#pragma unroll
    for (int off = 32; off; off >>= 1) s += __shfl_down(s, off, 64);
    __syncthreads();
    if ((tid & 63) == 0) sw[tid >> 6] = s;
    __syncthreads();
    if (tid == 0) {
        rmax[row] = mx;
        rsum[row] = sw[0] + sw[1] + sw[2] + sw[3];
    }
}

// ---------------------------------------------------------------------------
// Kernel 2: build cost matrix C[b][t][q]
// ---------------------------------------------------------------------------
__global__ __launch_bounds__(256) void build_cost(const float* __restrict__ outs,
                                                  const float* __restrict__ tpos,
                                                  const int* __restrict__ tids,
                                                  const float* __restrict__ rmax,
                                                  const float* __restrict__ rsum,
                                                  float* __restrict__ C) {
    int bt = blockIdx.x;             // b*T + t
    int b  = bt >> 8;
    int q  = threadIdx.x;

    int   id = tids[bt];
    float tx = tpos[2 * bt];
    float ty = tpos[2 * bt + 1];

    const float* orow = outs + (size_t)(b * QQ + q) * CD;
    float dx = orow[0] - tx;
    float dy = orow[1] - ty;
    float d  = sqrtf(dx * dx + dy * dy);
    float bbox = fminf(d, 100.0f);
    if (id <= 0) bbox = 100.0f;

    int   rq  = b * QQ + q;
    float cls = expf(orow[2 + id] - rmax[rq]) / rsum[rq];

    C[(size_t)bt * QQ + q] = bbox - cls;
}

// ---------------------------------------------------------------------------
// Kernel 3: EXACT reference JV, one wave per block (own CU).
// Inner loop = round-6 structure (value-only DPP min chain + ballot/ffs tail,
// measured 428 cy/iter — faster than payload-carrying DPP, r7 post-mortem).
// Scan epilogue = register augment walk (way packed 2x16b/lane, readlane
// chain) + parallel LDS path apply (replaces lane-0 serial LDS walk).
// Bitwise-identical arithmetic/trajectory to the reference.
// ---------------------------------------------------------------------------
template <int CTRL, int RM>
__device__ __forceinline__ float dppmin(float x) {
    int y = __builtin_amdgcn_update_dpp(__float_as_int(x), __float_as_int(x),
                                        CTRL, RM, 0xF, false);
    return fminf(x, __int_as_float(y));
}

__global__ __launch_bounds__(64) void jv_solve(const float* __restrict__ Call,
                                               float* __restrict__ outIdx) {
    const int b    = blockIdx.x;
    const int lane = threadIdx.x;
    const float* cost = Call + (size_t)b * NM * NM;

    __shared__ float u_s[NM + 1];
    __shared__ int   p_s[NM + 1];
    __shared__ int   path_s[NM + 1];
    extern __shared__ float crow[];          // [LROWS][NM]

    // stage rows 0..LROWS-1 into LDS (bit-identical copy)
#pragma unroll 4
    for (int r = 0; r < LROWS; ++r) {
        float4 x = *(const float4*)(cost + (size_t)r * NM + lane * 4);
        *(float4*)(crow + r * NM + lane * 4) = x;
    }
    for (int k = lane; k <= NM; k += 64) {
        u_s[k] = 0.0f;
        p_s[k] = -1;
    }
    // single wave: lockstep, no barriers needed anywhere

    float v[4] = {0.0f, 0.0f, 0.0f, 0.0f};   // column duals, persist

    for (int i = 0; i < NM; ++i) {
        // prefetch first row of this scan (row i)
        float4 cr;
        if (i < LROWS) cr = *(const float4*)(crow + i * NM + lane * 4);
        else           cr = *(const float4*)(cost + (size_t)i * NM + lane * 4);

        if (lane == 0) p_s[NM] = i;
        // p[j], u[p[j]] static during one scan
        int   pj[4];
        float ureg[4];
#pragma unroll
        for (int s = 0; s < 4; ++s) {
            pj[s]   = p_s[lane * 4 + s];
            ureg[s] = (pj[s] >= 0) ? u_s[pj[s]] : 0.0f;
        }
        const float uof0 = ureg[0], uof1 = ureg[1], uof2 = ureg[2], uof3 = ureg[3];
        float minv[4] = {BIGF, BIGF, BIGF, BIGF};
        int   way[4]  = {NM, NM, NM, NM};
        unsigned usedm = 0;
        float ui = 0.0f;
        int   j0 = NM;
        float u0 = 0.0f;

        while (true) {
            // mark j0 used (owner lane), before minv update — as reference
            if ((j0 >> 2) == lane) usedm |= 1u << (j0 & 3);

            float c4[4] = {cr.x, cr.y, cr.z, cr.w};
#pragma unroll
            for (int s = 0; s < 4; ++s) {
                float cur = c4[s] - u0 - v[s];
                bool  un  = !(usedm & (1u << s));
                if (un && cur < minv[s]) { minv[s] = cur; way[s] = j0; }
            }

            // local argmin over 4 slots with payload (first-index tie-break)
            float cand[4];
#pragma unroll
            for (int s = 0; s < 4; ++s)
                cand[s] = (usedm & (1u << s)) ? BIGF : minv[s];
            float cA = cand[0]; int lsA = 0; int pA = pj[0]; float uA = uof0;
            if (cand[1] < cA) { cA = cand[1]; lsA = 1; pA = pj[1]; uA = uof1; }
            float cB = cand[2]; int lsB = 2; int pB = pj[2]; float uB = uof2;
            if (cand[3] < cB) { cB = cand[3]; lsB = 3; pB = pj[3]; uB = uof3; }
            if (cB < cA)      { cA = cB;      lsA = lsB; pA = pB;  uA = uB;  }

            // wave-wide min via DPP (VALU pipe only), result in lane 63
            float x = cA;
            x = dppmin<0x111, 0xF>(x);   // row_shr:1
            x = dppmin<0x112, 0xF>(x);   // row_shr:2
            x = dppmin<0x114, 0xF>(x);   // row_shr:4
            x = dppmin<0x118, 0xF>(x);   // row_shr:8
            x = dppmin<0x142, 0xA>(x);   // row_bcast:15 -> rows 1,3
            x = dppmin<0x143, 0xC>(x);   // row_bcast:31 -> rows 2,3
            float wv = __int_as_float(__builtin_amdgcn_readlane(__float_as_int(x), 63));

            unsigned long long mm = __ballot(cA == wv);
            int flane = __ffsll(mm) - 1;             // lowest tied lane
            int   pk  = ((pA + 1) << 2) | lsA;       // packed (pj+1, slot)
            int   wpk = __builtin_amdgcn_readlane(pk, flane);
            float u0n = __int_as_float(__builtin_amdgcn_readlane(__float_as_int(uA), flane));
            int   i0n = (wpk >> 2) - 1;
            int   j1  = flane * 4 + (wpk & 3);
            float delta = wv;

            // prefetch next row before the delta updates (overlap latency)
            if (i0n >= 0) {
                if (i0n < LROWS) cr = *(const float4*)(crow + i0n * NM + lane * 4);
                else             cr = *(const float4*)(cost + (size_t)i0n * NM + lane * 4);
            }

            // updates, same order/arithmetic as reference
            ui += delta;
#pragma unroll
            for (int s = 0; s < 4; ++s) {
                if (usedm & (1u << s)) { v[s] -= delta; ureg[s] += delta; }
                else                   { minv[s] -= delta; }
            }
            j0 = j1;
            if (i0n < 0) break;
            u0 = u0n;
        }

        // write back u for used slots (distinct rows)
#pragma unroll
        for (int s = 0; s < 4; ++s)
            if (usedm & (1u << s)) u_s[pj[s]] = ureg[s];
        if (lane == 0) u_s[i] = ui;

        // augment walk in registers: way packed 2x16b per lane (r7's win)
        unsigned wlo = (unsigned)way[0] | ((unsigned)way[1] << 16);
        unsigned whi = (unsigned)way[2] | ((unsigned)way[3] << 16);
        int jj = j0, m = 0;
        while (jj != NM) {
            if (lane == 0) path_s[m] = jj;
            int l  = jj >> 2;
            int lo = __builtin_amdgcn_readlane((int)wlo, l);
            int hi = __builtin_amdgcn_readlane((int)whi, l);
            int wd = (jj & 2) ? hi : lo;
            jj = (jj & 1) ? ((wd >> 16) & 0xffff) : (wd & 0xffff);
            ++m;
        }
        if (lane == 0) path_s[m] = NM;      // terminator: p_s[NM] == i

        // parallel path shift: p[path[k]] = p_old[path[k+1]]
        // (path nodes distinct; within a 64-batch all reads precede writes,
        //  across batches read/write sets are disjoint)
        for (int base = 0; base < m; base += 64) {
            int k = base + lane;
            if (k < m) {
                int nd = path_s[k];
                int pv = p_s[path_s[k + 1]];
                p_s[nd] = pv;
            }
        }
    }

    // outputs as float32: indices[0]=rows (arange), indices[1]=cols
#pragma unroll
    for (int s = 0; s < 4; ++s) {
        int j = lane * 4 + s;
        outIdx[b * TT + j] = (float)j;
        int r = p_s[j];
        outIdx[BB * TT + b * TT + r] = (float)j;
    }
}

// ---------------------------------------------------------------------------
extern "C" void kernel_launch(void* const* d_in, const int* in_sizes, int n_in,
                              void* d_out, int out_size, void* d_ws, size_t ws_size,
                              hipStream_t stream) {
    const float* outs = (const float*)d_in[0];   // (B,Q,258) f32
    const float* tpos = (const float*)d_in[1];   // (B,T,2)   f32
    const int*   tids = (const int*)d_in[2];     // (B,T)     i32

    float* out  = (float*)d_out;
    float* C    = out + 2 * BB * TT;
    float* rmax = (float*)d_ws;
    float* rsum = rmax + BB * QQ;

    hipLaunchKernelGGL(sm_stats,   dim3(BB * QQ), dim3(256), 0, stream, outs, rmax, rsum);
    hipLaunchKernelGGL(build_cost, dim3(BB * TT), dim3(256), 0, stream, outs, tpos, tids, rmax, rsum, C);
    hipLaunchKernelGGL(jv_solve,   dim3(BB),      dim3(64),
                       LROWS * NM * sizeof(float), stream, C, out);
}

// Round 9
// 2663.479 us; speedup vs baseline: 1.1490x; 1.0600x over previous
//
#include <hip/hip_runtime.h>
#include <hip/hip_bf16.h>

#define BB   64
#define QQ   256
#define TT   256
#define CD   258          // 2 + NC
#define NM   256          // square assignment size
#define BIGF 1000000000.0f
#define LROWS 152         // rows cached in LDS (152 KB dynamic, proven r8)

// ---------------------------------------------------------------------------
// Kernel 1: per-(b,q) softmax stats (max and sum of exp(x-max)) over NC=256
// ---------------------------------------------------------------------------
__global__ __launch_bounds__(256) void sm_stats(const float* __restrict__ outs,
                                                float* __restrict__ rmax,
                                                float* __restrict__ rsum) {
    int row = blockIdx.x;            // b*Q + q
    int tid = threadIdx.x;
    float x = outs[(size_t)row * CD + 2 + tid];

    __shared__ float sw[5];
    float m = x;
#pragma unroll
    for (int off = 32; off; off >>= 1) m = fmaxf(m, __shfl_down(m, off, 64));
    if ((tid & 63) == 0) sw[tid >> 6] = m;
    __syncthreads();
    if (tid == 0) sw[4] = fmaxf(fmaxf(sw[0], sw[1]), fmaxf(sw[2], sw[3]));
    __syncthreads();
    float mx = sw[4];

    float s = expf(x - mx);
#pragma unroll
    for (int off = 32; off; off >>= 1) s += __shfl_down(s, off, 64);
    __syncthreads();
    if ((tid & 63) == 0) sw[tid >> 6] = s;
    __syncthreads();
    if (tid == 0) {
        rmax[row] = mx;
        rsum[row] = sw[0] + sw[1] + sw[2] + sw[3];
    }
}

// ---------------------------------------------------------------------------
// Kernel 2: build cost matrix C[b][t][q]
// ---------------------------------------------------------------------------
__global__ __launch_bounds__(256) void build_cost(const float* __restrict__ outs,
                                                  const float* __restrict__ tpos,
                                                  const int* __restrict__ tids,
                                                  const float* __restrict__ rmax,
                                                  const float* __restrict__ rsum,
                                                  float* __restrict__ C) {
    int bt = blockIdx.x;             // b*T + t
    int b  = bt >> 8;
    int q  = threadIdx.x;

    int   id = tids[bt];
    float tx = tpos[2 * bt];
    float ty = tpos[2 * bt + 1];

    const float* orow = outs + (size_t)(b * QQ + q) * CD;
    float dx = orow[0] - tx;
    float dy = orow[1] - ty;
    float d  = sqrtf(dx * dx + dy * dy);
    float bbox = fminf(d, 100.0f);
    if (id <= 0) bbox = 100.0f;

    int   rq  = b * QQ + q;
    float cls = expf(orow[2 + id] - rmax[rq]) / rsum[rq];

    C[(size_t)bt * QQ + q] = bbox - cls;
}

// ---------------------------------------------------------------------------
// Kernel 3: EXACT reference JV, one wave per block (own CU). r6 structure
// (value-only DPP min + ballot/ffs tail, lane-0 serial LDS augment walk —
// both measured-best) with: minv folded to BIGF at mark time (kills cand[]
// masking on the critical path), next-scan row load hoisted over the scan
// epilogue, b128 p_s prologue gather, LROWS=152.
// NOTE (r8 lesson): readlane with non-provably-uniform index => waterfall
// loop; the register augment walk was a regression. Keep the LDS walk.
// Bitwise-identical arithmetic/trajectory to the reference.
// ---------------------------------------------------------------------------
template <int CTRL, int RM>
__device__ __forceinline__ float dppmin(float x) {
    int y = __builtin_amdgcn_update_dpp(__float_as_int(x), __float_as_int(x),
                                        CTRL, RM, 0xF, false);
    return fminf(x, __int_as_float(y));
}

__global__ __launch_bounds__(64) void jv_solve(const float* __restrict__ Call,
                                               float* __restrict__ outIdx) {
    const int b    = blockIdx.x;
    const int lane = threadIdx.x;
    const float* cost = Call + (size_t)b * NM * NM;

    __shared__ float u_s[NM + 1];
    __shared__ int   p_s[NM + 1];
    __shared__ int   way_s[NM];
    extern __shared__ float crow[];          // [LROWS][NM]

    // stage rows 0..LROWS-1 into LDS (bit-identical copy)
#pragma unroll 4
    for (int r = 0; r < LROWS; ++r) {
        float4 x = *(const float4*)(cost + (size_t)r * NM + lane * 4);
        *(float4*)(crow + r * NM + lane * 4) = x;
    }
    for (int k = lane; k <= NM; k += 64) {
        u_s[k] = 0.0f;
        p_s[k] = -1;
        if (k < NM) way_s[k] = NM;
    }
    // single wave: lockstep, no barriers needed anywhere

    float v[4] = {0.0f, 0.0f, 0.0f, 0.0f};   // column duals, persist

    // first scan's first row (row 0 is in crow)
    float4 cr0 = *(const float4*)(crow + 0 * NM + lane * 4);

    for (int i = 0; i < NM; ++i) {
        float4 cr = cr0;                     // hoisted load from prev scan end

        if (lane == 0) p_s[NM] = i;
        // p[j], u[p[j]] static during one scan; p_s slice as one b128
        int4 pjv = *(const int4*)(p_s + lane * 4);
        int  pj[4] = {pjv.x, pjv.y, pjv.z, pjv.w};
        float ureg[4];
#pragma unroll
        for (int s = 0; s < 4; ++s)
            ureg[s] = (pj[s] >= 0) ? u_s[pj[s]] : 0.0f;
        const float uof0 = ureg[0], uof1 = ureg[1], uof2 = ureg[2], uof3 = ureg[3];
        float minv[4] = {BIGF, BIGF, BIGF, BIGF};
        int   way[4]  = {NM, NM, NM, NM};
        unsigned usedm = 0;
        float ui = 0.0f;
        int   j0 = NM;
        float u0 = 0.0f;

        while (true) {
            // mark j0 used (owner lane) and fold minv[j0]=BIGF — runs in the
            // row-load shadow; removes cand[] masking from the critical path
            {
                bool own = (j0 >> 2) == lane;
                if (own) usedm |= 1u << (j0 & 3);
#pragma unroll
                for (int s = 0; s < 4; ++s) {
                    bool mk = own && ((j0 & 3) == s);
                    minv[s] = mk ? BIGF : minv[s];
                }
            }

            float c4[4] = {cr.x, cr.y, cr.z, cr.w};
#pragma unroll
            for (int s = 0; s < 4; ++s) {
                float cur = c4[s] - u0 - v[s];
                bool  un  = !(usedm & (1u << s));
                if (un && cur < minv[s]) { minv[s] = cur; way[s] = j0; }
            }

            // local argmin over 4 slots with payload (first-index tie-break);
            // used slots hold BIGF == reference's masked big
            float cA = minv[0]; int lsA = 0; int pA = pj[0]; float uA = uof0;
            if (minv[1] < cA) { cA = minv[1]; lsA = 1; pA = pj[1]; uA = uof1; }
            float cB = minv[2]; int lsB = 2; int pB = pj[2]; float uB = uof2;
            if (minv[3] < cB) { cB = minv[3]; lsB = 3; pB = pj[3]; uB = uof3; }
            if (cB < cA)      { cA = cB;      lsA = lsB; pA = pB;  uA = uB;  }

            // wave-wide min via DPP (VALU pipe only), result in lane 63
            float x = cA;
            x = dppmin<0x111, 0xF>(x);   // row_shr:1
            x = dppmin<0x112, 0xF>(x);   // row_shr:2
            x = dppmin<0x114, 0xF>(x);   // row_shr:4
            x = dppmin<0x118, 0xF>(x);   // row_shr:8
            x = dppmin<0x142, 0xA>(x);   // row_bcast:15 -> rows 1,3
            x = dppmin<0x143, 0xC>(x);   // row_bcast:31 -> rows 2,3
            float wv = __int_as_float(__builtin_amdgcn_readlane(__float_as_int(x), 63));

            unsigned long long mm = __ballot(cA == wv);
            int flane = __ffsll(mm) - 1;             // lowest tied lane
            int   pk  = ((pA + 1) << 2) | lsA;       // packed (pj+1, slot)
            int   wpk = __builtin_amdgcn_readlane(pk, flane);
            float u0n = __int_as_float(__builtin_amdgcn_readlane(__float_as_int(uA), flane));
            int   i0n = (wpk >> 2) - 1;
            int   j1  = flane * 4 + (wpk & 3);
            float delta = wv;

            // prefetch next row before the delta updates (overlap latency)
            if (i0n >= 0) {
                if (i0n < LROWS) cr = *(const float4*)(crow + i0n * NM + lane * 4);
                else             cr = *(const float4*)(cost + (size_t)i0n * NM + lane * 4);
            }

            // updates, same order/arithmetic as reference
            ui += delta;
#pragma unroll
            for (int s = 0; s < 4; ++s) {
                if (usedm & (1u << s)) { v[s] -= delta; ureg[s] += delta; }
                else                   { minv[s] -= delta; }
            }
            j0 = j1;
            if (i0n < 0) break;
            u0 = u0n;
        }

        // hoist next scan's first row load over the epilogue (row i+1 known)
        if (i + 1 < NM) {
            int in2 = i + 1;
            if (in2 < LROWS) cr0 = *(const float4*)(crow + in2 * NM + lane * 4);
            else             cr0 = *(const float4*)(cost + (size_t)in2 * NM + lane * 4);
        }

        // write back per-scan state
#pragma unroll
        for (int s = 0; s < 4; ++s) {
            way_s[lane * 4 + s] = way[s];
            if (usedm & (1u << s)) u_s[pj[s]] = ureg[s];
        }
        if (lane == 0) {
            u_s[i] = ui;
            // augmenting path flip (serial LDS walk — measured-best, r8)
            int jj = j0;
            while (jj != NM) {
                int j1w = way_s[jj];
                p_s[jj] = p_s[j1w];
                jj = j1w;
            }
        }
    }

    // outputs as float32: indices[0]=rows (arange), indices[1]=cols
#pragma unroll
    for (int s = 0; s < 4; ++s) {
        int j = lane * 4 + s;
        outIdx[b * TT + j] = (float)j;
        int r = p_s[j];
        outIdx[BB * TT + b * TT + r] = (float)j;
    }
}

// ---------------------------------------------------------------------------
extern "C" void kernel_launch(void* const* d_in, const int* in_sizes, int n_in,
                              void* d_out, int out_size, void* d_ws, size_t ws_size,
                              hipStream_t stream) {
    const float* outs = (const float*)d_in[0];   // (B,Q,258) f32
    const float* tpos = (const float*)d_in[1];   // (B,T,2)   f32
    const int*   tids = (const int*)d_in[2];     // (B,T)     i32

    float* out  = (float*)d_out;
    float* C    = out + 2 * BB * TT;
    float* rmax = (float*)d_ws;
    float* rsum = rmax + BB * QQ;

    hipLaunchKernelGGL(sm_stats,   dim3(BB * QQ), dim3(256), 0, stream, outs, rmax, rsum);
    hipLaunchKernelGGL(build_cost, dim3(BB * TT), dim3(256), 0, stream, outs, tpos, tids, rmax, rsum, C);
    hipLaunchKernelGGL(jv_solve,   dim3(BB),      dim3(64),
                       LROWS * NM * sizeof(float), stream, C, out);
}

// Round 11
// 2523.544 us; speedup vs baseline: 1.2127x; 1.0555x over previous
//
#include <hip/hip_runtime.h>
#include <hip/hip_bf16.h>

#define BB   64
#define QQ   256
#define TT   256
#define CD   258          // 2 + NC
#define NM   256          // square assignment size
#define BIGF 1000000000.0f
#define LROWS 128         // rows cached in LDS (128 KB) — r6 measured-best

// ---------------------------------------------------------------------------
// Kernel 1: per-(b,q) softmax stats (max and sum of exp(x-max)) over NC=256
// ---------------------------------------------------------------------------
__global__ __launch_bounds__(256) void sm_stats(const float* __restrict__ outs,
                                                float* __restrict__ rmax,
                                                float* __restrict__ rsum) {
    int row = blockIdx.x;            // b*Q + q
    int tid = threadIdx.x;
    float x = outs[(size_t)row * CD + 2 + tid];

    __shared__ float sw[5];
    float m = x;
#pragma unroll
    for (int off = 32; off; off >>= 1) m = fmaxf(m, __shfl_down(m, off, 64));
    if ((tid & 63) == 0) sw[tid >> 6] = m;
    __syncthreads();
    if (tid == 0) sw[4] = fmaxf(fmaxf(sw[0], sw[1]), fmaxf(sw[2], sw[3]));
    __syncthreads();
    float mx = sw[4];

    float s = expf(x - mx);
#pragma unroll
    for (int off = 32; off; off >>= 1) s += __shfl_down(s, off, 64);
    __syncthreads();
    if ((tid & 63) == 0) sw[tid >> 6] = s;
    __syncthreads();
    if (tid == 0) {
        rmax[row] = mx;
        rsum[row] = sw[0] + sw[1] + sw[2] + sw[3];
    }
}

// ---------------------------------------------------------------------------
// Kernel 2: build cost matrix C[b][t][q]
// ---------------------------------------------------------------------------
__global__ __launch_bounds__(256) void build_cost(const float* __restrict__ outs,
                                                  const float* __restrict__ tpos,
                                                  const int* __restrict__ tids,
                                                  const float* __restrict__ rmax,
                                                  const float* __restrict__ rsum,
                                                  float* __restrict__ C) {
    int bt = blockIdx.x;             // b*T + t
    int b  = bt >> 8;
    int q  = threadIdx.x;

    int   id = tids[bt];
    float tx = tpos[2 * bt];
    float ty = tpos[2 * bt + 1];

    const float* orow = outs + (size_t)(b * QQ + q) * CD;
    float dx = orow[0] - tx;
    float dy = orow[1] - ty;
    float d  = sqrtf(dx * dx + dy * dy);
    float bbox = fminf(d, 100.0f);
    if (id <= 0) bbox = 100.0f;

    int   rq  = b * QQ + q;
    float cls = expf(orow[2 + id] - rmax[rq]) / rsum[rq];

    C[(size_t)bt * QQ + q] = bbox - cls;
}

// ---------------------------------------------------------------------------
// Kernel 3: EXACT reference JV, ONE WAVE PER BLOCK (own CU). Round-6 version
// verbatim — measured champion (jv_solve 2426 us). Value-only DPP min chain
// + ballot/ffs tail; lane-0 serial LDS augment walk; LROWS=128.
// Post-r6 variants all regressed: payload-DPP (+526), reg augment walk
// (+296; non-uniform readlane => waterfall), minv-fold/hoist/b128 (+126).
// Bitwise-identical arithmetic/trajectory to the reference.
// ---------------------------------------------------------------------------
template <int CTRL, int RM>
__device__ __forceinline__ float dppmin(float x) {
    int y = __builtin_amdgcn_update_dpp(__float_as_int(x), __float_as_int(x),
                                        CTRL, RM, 0xF, false);
    return fminf(x, __int_as_float(y));
}

__global__ __launch_bounds__(64) void jv_solve(const float* __restrict__ Call,
                                               float* __restrict__ outIdx) {
    const int b    = blockIdx.x;
    const int lane = threadIdx.x;
    const float* cost = Call + (size_t)b * NM * NM;

    __shared__ float u_s[NM + 1];
    __shared__ int   p_s[NM + 1];
    __shared__ int   way_s[NM];
    extern __shared__ float crow[];          // [LROWS][NM] = 128 KB

    // stage rows 0..LROWS-1 into LDS (bit-identical copy)
#pragma unroll 4
    for (int r = 0; r < LROWS; ++r) {
        float4 x = *(const float4*)(cost + (size_t)r * NM + lane * 4);
        *(float4*)(crow + r * NM + lane * 4) = x;
    }
    for (int k = lane; k <= NM; k += 64) {
        u_s[k] = 0.0f;
        p_s[k] = -1;
        if (k < NM) way_s[k] = NM;
    }
    // single wave: lockstep, no barriers needed anywhere

    float v[4] = {0.0f, 0.0f, 0.0f, 0.0f};   // column duals, persist

    for (int i = 0; i < NM; ++i) {
        // prefetch first row of this scan (row i)
        float4 cr;
        if (i < LROWS) cr = *(const float4*)(crow + i * NM + lane * 4);
        else           cr = *(const float4*)(cost + (size_t)i * NM + lane * 4);

        if (lane == 0) p_s[NM] = i;
        // p[j], u[p[j]] static during one scan
        int   pj[4];
        float ureg[4];
#pragma unroll
        for (int s = 0; s < 4; ++s) {
            pj[s]   = p_s[lane * 4 + s];
            ureg[s] = (pj[s] >= 0) ? u_s[pj[s]] : 0.0f;
        }
        const float uof0 = ureg[0], uof1 = ureg[1], uof2 = ureg[2], uof3 = ureg[3];
        float minv[4] = {BIGF, BIGF, BIGF, BIGF};
        int   way[4]  = {NM, NM, NM, NM};
        unsigned usedm = 0;
        float ui = 0.0f;
        int   j0 = NM;
        float u0 = 0.0f;

        while (true) {
            // mark j0 used (owner lane), before minv update — as reference
            if ((j0 >> 2) == lane) usedm |= 1u << (j0 & 3);

            float c4[4] = {cr.x, cr.y, cr.z, cr.w};
#pragma unroll
            for (int s = 0; s < 4; ++s) {
                float cur = c4[s] - u0 - v[s];
                bool  un  = !(usedm & (1u << s));
                if (un && cur < minv[s]) { minv[s] = cur; way[s] = j0; }
            }

            // local argmin over 4 slots with payload (first-index tie-break)
            float cand[4];
#pragma unroll
            for (int s = 0; s < 4; ++s)
                cand[s] = (usedm & (1u << s)) ? BIGF : minv[s];
            float cA = cand[0]; int lsA = 0; int pA = pj[0]; float uA = uof0;
            if (cand[1] < cA) { cA = cand[1]; lsA = 1; pA = pj[1]; uA = uof1; }
            float cB = cand[2]; int lsB = 2; int pB = pj[2]; float uB = uof2;
            if (cand[3] < cB) { cB = cand[3]; lsB = 3; pB = pj[3]; uB = uof3; }
            if (cB < cA)      { cA = cB;      lsA = lsB; pA = pB;  uA = uB;  }

            // wave-wide min via DPP (VALU pipe only), result in lane 63
            float x = cA;
            x = dppmin<0x111, 0xF>(x);   // row_shr:1
            x = dppmin<0x112, 0xF>(x);   // row_shr:2
            x = dppmin<0x114, 0xF>(x);   // row_shr:4
            x = dppmin<0x118, 0xF>(x);   // row_shr:8
            x = dppmin<0x142, 0xA>(x);   // row_bcast:15 -> rows 1,3
            x = dppmin<0x143, 0xC>(x);   // row_bcast:31 -> rows 2,3
            float wv = __int_as_float(__builtin_amdgcn_readlane(__float_as_int(x), 63));

            unsigned long long mm = __ballot(cA == wv);
            int flane = __ffsll(mm) - 1;             // lowest tied lane
            int   pk  = ((pA + 1) << 2) | lsA;       // packed (pj+1, slot)
            int   wpk = __builtin_amdgcn_readlane(pk, flane);
            float u0n = __int_as_float(__builtin_amdgcn_readlane(__float_as_int(uA), flane));
            int   i0n = (wpk >> 2) - 1;
            int   j1  = flane * 4 + (wpk & 3);
            float delta = wv;

            // prefetch next row before the delta updates (overlap latency)
            if (i0n >= 0) {
                if (i0n < LROWS) cr = *(const float4*)(crow + i0n * NM + lane * 4);
                else             cr = *(const float4*)(cost + (size_t)i0n * NM + lane * 4);
            }

            // updates, same order/arithmetic as reference
            ui += delta;
#pragma unroll
            for (int s = 0; s < 4; ++s) {
                if (usedm & (1u << s)) { v[s] -= delta; ureg[s] += delta; }
                else                   { minv[s] -= delta; }
            }
            j0 = j1;
            if (i0n < 0) break;
            u0 = u0n;
        }

        // write back per-scan state
#pragma unroll
        for (int s = 0; s < 4; ++s) {
            way_s[lane * 4 + s] = way[s];
            if (usedm & (1u << s)) u_s[pj[s]] = ureg[s];
        }
        if (lane == 0) {
            u_s[i] = ui;
            // augmenting path flip (serial LDS walk — measured-best)
            int jj = j0;
            while (jj != NM) {
                int j1w = way_s[jj];
                p_s[jj] = p_s[j1w];
                jj = j1w;
            }
        }
    }

    // outputs as float32: indices[0]=rows (arange), indices[1]=cols
#pragma unroll
    for (int s = 0; s < 4; ++s) {
        int j = lane * 4 + s;
        outIdx[b * TT + j] = (float)j;
        int r = p_s[j];
        outIdx[BB * TT + b * TT + r] = (float)j;
    }
}

// ---------------------------------------------------------------------------
extern "C" void kernel_launch(void* const* d_in, const int* in_sizes, int n_in,
                              void* d_out, int out_size, void* d_ws, size_t ws_size,
                              hipStream_t stream) {
    const float* outs = (const float*)d_in[0];   // (B,Q,258) f32
    const float* tpos = (const float*)d_in[1];   // (B,T,2)   f32
    const int*   tids = (const int*)d_in[2];     // (B,T)     i32

    float* out  = (float*)d_out;
    float* C    = out + 2 * BB * TT;
    float* rmax = (float*)d_ws;
    float* rsum = rmax + BB * QQ;

    hipLaunchKernelGGL(sm_stats,   dim3(BB * QQ), dim3(256), 0, stream, outs, rmax, rsum);
    hipLaunchKernelGGL(build_cost, dim3(BB * TT), dim3(256), 0, stream, outs, tpos, tids, rmax, rsum, C);
    hipLaunchKernelGGL(jv_solve,   dim3(BB),      dim3(64),
                       LROWS * NM * sizeof(float), stream, C, out);
}